// Round 6
// baseline (336.968 us; speedup 1.0000x reference)
//
#include <hip/hip_runtime.h>

// B=32, L=T=S=128, D=512, M = B*L = 4096.
#define DD 512
#define SS 128
#define TT4 4          // t-rows per attn block
#define SCH16 16       // s-chunk rows staged in LDS
#define RW 520         // LDS row width in shorts (65 x 16B chunks -> quad-stride 1)
#define C2F 2.8853900817779268f   // 2*log2(e)
#define L2EF 1.4426950408889634f

typedef __bf16 bf16x8 __attribute__((ext_vector_type(8)));
typedef float f32x4 __attribute__((ext_vector_type(4)));
typedef unsigned int uint32x4 __attribute__((ext_vector_type(4)));

__device__ __forceinline__ unsigned short f2bf(float f) {
    unsigned int u = __builtin_bit_cast(unsigned int, f);
    u += 0x7fffu + ((u >> 16) & 1u);            // RTNE
    return (unsigned short)(u >> 16);
}
__device__ __forceinline__ float bflo(unsigned int u) { return __builtin_bit_cast(float, u << 16); }
__device__ __forceinline__ float bfhi(unsigned int u) { return __builtin_bit_cast(float, u & 0xffff0000u); }

// ---------------------------------------------------------------------------
// f32 -> bf16 for BOTH activation tensors in one dispatch. grid = 2*n8/256.
// ---------------------------------------------------------------------------
__global__ __launch_bounds__(256)
void cvt_dual(const float* __restrict__ a, const float* __restrict__ b,
              unsigned short* __restrict__ oa, unsigned short* __restrict__ ob, int n8)
{
    int i = blockIdx.x * 256 + threadIdx.x;
    const float* in; unsigned short* out; int k;
    if (i < n8) { in = a; out = oa; k = i; }
    else        { in = b; out = ob; k = i - n8; }
    const float4 x = ((const float4*)in)[2 * k];
    const float4 y = ((const float4*)in)[2 * k + 1];
    uint32x4 o;
    o[0] = (unsigned)f2bf(x.x) | ((unsigned)f2bf(x.y) << 16);
    o[1] = (unsigned)f2bf(x.z) | ((unsigned)f2bf(x.w) << 16);
    o[2] = (unsigned)f2bf(y.x) | ((unsigned)f2bf(y.y) << 16);
    o[3] = (unsigned)f2bf(y.z) | ((unsigned)f2bf(y.w) << 16);
    ((uint32x4*)out)[k] = o;
}

// ---------------------------------------------------------------------------
// All weight transposes in one dispatch. grid (8, 8, 4).
// z=0: Wq[512,512] -> Wqct[0..]; z=1: Wc -> Wqct[512*512..];
// z=2,3: Wout[1024,512] halves -> Woutt[512,1024].
// ---------------------------------------------------------------------------
__global__ __launch_bounds__(256)
void transpose_all(const float* __restrict__ Wq, const float* __restrict__ Wc,
                   const float* __restrict__ Wout,
                   unsigned short* __restrict__ Wqct, unsigned short* __restrict__ Woutt)
{
    __shared__ float t[64][65];
    const int z = blockIdx.z;
    const float* in; unsigned short* out; int R, r0;
    if (z == 0)      { in = Wq;   out = Wqct;             R = 512;  r0 = blockIdx.y * 64; }
    else if (z == 1) { in = Wc;   out = Wqct + 512 * 512; R = 512;  r0 = blockIdx.y * 64; }
    else             { in = Wout; out = Woutt;            R = 1024; r0 = (z - 2) * 512 + blockIdx.y * 64; }
    const int c0 = blockIdx.x * 64;
    const int tid = threadIdx.x;
    const int lc = tid & 63, lr = tid >> 6;
    #pragma unroll
    for (int i = 0; i < 16; ++i) {
        int r = lr + i * 4;
        t[r][lc] = in[(size_t)(r0 + r) * 512 + c0 + lc];
    }
    __syncthreads();
    #pragma unroll
    for (int i = 0; i < 16; ++i) {
        int rr = lr + i * 4;
        out[(size_t)(c0 + rr) * R + r0 + lc] = f2bf(t[lc][rr]);
    }
}

// ---------------------------------------------------------------------------
// Projection GEMM, z-batched over the two inputs.
// X[4096,512]bf16 @ Wqct[1024,512]^T: cols<512 -> (X@Wq+bq)*C2 (bf16 wq_out),
// cols>=512 -> X@Wc (bf16 uh_out). 128x64 tile, BK=64, 256 thr. grid (16,32,2).
// ---------------------------------------------------------------------------
__global__ __launch_bounds__(256)
void gemm_proj(const unsigned short* __restrict__ A0, const unsigned short* __restrict__ A1,
               const unsigned short* __restrict__ Bt, const float* __restrict__ bq,
               unsigned short* __restrict__ w0, unsigned short* __restrict__ u0,
               unsigned short* __restrict__ w1, unsigned short* __restrict__ u1)
{
    constexpr int K = 512, LDA = 72;
    __shared__ __align__(16) unsigned short As[128][LDA];
    __shared__ __align__(16) unsigned short Bs[64][LDA];

    const unsigned short* A = blockIdx.z ? A1 : A0;
    unsigned short* outW    = blockIdx.z ? w1 : w0;
    unsigned short* outU    = blockIdx.z ? u1 : u0;

    const int tid = threadIdx.x;
    const int n0 = blockIdx.x * 64, m0 = blockIdx.y * 128;
    const int lane = tid & 63, wid = tid >> 6;
    const int wr = wid >> 1, wc = wid & 1;
    const int lr = lane & 15, kb = lane >> 4;

    f32x4 acc[4][2] = {};
    uint32x4 ra[4], rb[2];

    auto LOADK = [&](int k0) {
        #pragma unroll
        for (int j = 0; j < 4; ++j) {
            int id = tid + 256 * j; int r = id >> 3, s = id & 7;
            ra[j] = *(const uint32x4*)&A[(size_t)(m0 + r) * K + k0 + s * 8];
        }
        #pragma unroll
        for (int j = 0; j < 2; ++j) {
            int id = tid + 256 * j; int r = id >> 3, s = id & 7;
            rb[j] = *(const uint32x4*)&Bt[(size_t)(n0 + r) * K + k0 + s * 8];
        }
    };

    LOADK(0);
    #pragma unroll 1
    for (int step = 0; step < K / 64; ++step) {
        __syncthreads();
        #pragma unroll
        for (int j = 0; j < 4; ++j) {
            int id = tid + 256 * j; int r = id >> 3, s = id & 7;
            *(uint32x4*)&As[r][s * 8] = ra[j];
        }
        #pragma unroll
        for (int j = 0; j < 2; ++j) {
            int id = tid + 256 * j; int r = id >> 3, s = id & 7;
            *(uint32x4*)&Bs[r][s * 8] = rb[j];
        }
        __syncthreads();
        if (step + 1 < K / 64) LOADK((step + 1) * 64);
        #pragma unroll
        for (int kk = 0; kk < 64; kk += 32) {
            bf16x8 b0 = __builtin_bit_cast(bf16x8, *(const uint32x4*)&Bs[wc * 32 + lr][kk + kb * 8]);
            bf16x8 b1 = __builtin_bit_cast(bf16x8, *(const uint32x4*)&Bs[wc * 32 + 16 + lr][kk + kb * 8]);
            #pragma unroll
            for (int mf = 0; mf < 4; ++mf) {
                bf16x8 a0 = __builtin_bit_cast(bf16x8, *(const uint32x4*)&As[wr * 64 + mf * 16 + lr][kk + kb * 8]);
                acc[mf][0] = __builtin_amdgcn_mfma_f32_16x16x32_bf16(a0, b0, acc[mf][0], 0, 0, 0);
                acc[mf][1] = __builtin_amdgcn_mfma_f32_16x16x32_bf16(a0, b1, acc[mf][1], 0, 0, 0);
            }
        }
    }

    #pragma unroll
    for (int nf = 0; nf < 2; ++nf) {
        const int col = n0 + wc * 32 + nf * 16 + lr;
        const float bv = (col < 512) ? bq[col] : 0.0f;
        #pragma unroll
        for (int mf = 0; mf < 4; ++mf) {
            const int row = m0 + wr * 64 + mf * 16 + kb * 4;
            #pragma unroll
            for (int r = 0; r < 4; ++r) {
                const float valf = acc[mf][nf][r];
                if (col < 512) outW[(size_t)(row + r) * 512 + col] = f2bf((valf + bv) * C2F);
                else           outU[(size_t)(row + r) * 512 + (col - 512)] = f2bf(valf);
            }
        }
    }
}

// ---------------------------------------------------------------------------
// Final GEMM, A fused on the fly:
// A[m][k] = k<512 ? mix(c1,c2)[m][k] (bf16) : mix(no,cs)[m][k-512] (f32->bf16)
// out[4096,512] f32 = A @ Woutt[512,1024]^T + bout. 128x64 tile. grid (8,32).
// ---------------------------------------------------------------------------
__global__ __launch_bounds__(256)
void gemm_final(const unsigned short* __restrict__ c1, const unsigned short* __restrict__ c2,
                const float* __restrict__ no, const float* __restrict__ cs,
                const float* __restrict__ mix, const unsigned short* __restrict__ Bt,
                const float* __restrict__ bout, float* __restrict__ out)
{
    constexpr int K = 1024, LDA = 72;
    __shared__ __align__(16) unsigned short As[128][LDA];
    __shared__ __align__(16) unsigned short Bs[64][LDA];

    const int tid = threadIdx.x;
    const int n0 = blockIdx.x * 64, m0 = blockIdx.y * 128;
    const int lane = tid & 63, wid = tid >> 6;
    const int wr = wid >> 1, wc = wid & 1;
    const int lr = lane & 15, kb = lane >> 4;
    const float mxv = mix[0], omv = 1.0f - mxv;

    f32x4 acc[4][2] = {};
    uint32x4 ra[4], rb[2];

    auto LOADK = [&](int k0) {
        #pragma unroll
        for (int j = 0; j < 4; ++j) {
            int id = tid + 256 * j; int r = id >> 3, s = id & 7;
            const size_t row = m0 + r;
            const int k = k0 + s * 8;
            uint32x4 o;
            if (k < 512) {
                const uint32x4 x1 = *(const uint32x4*)&c1[row * 512 + k];
                const uint32x4 x2 = *(const uint32x4*)&c2[row * 512 + k];
                #pragma unroll
                for (int q = 0; q < 4; ++q) {
                    float lo = omv * bflo(x1[q]) + mxv * bflo(x2[q]);
                    float hi = omv * bfhi(x1[q]) + mxv * bfhi(x2[q]);
                    o[q] = (unsigned)f2bf(lo) | ((unsigned)f2bf(hi) << 16);
                }
            } else {
                const float* n1 = &no[row * 512 + k - 512];
                const float* s1 = &cs[row * 512 + k - 512];
                const float4 a1 = *(const float4*)n1, a2 = *(const float4*)(n1 + 4);
                const float4 b1 = *(const float4*)s1, b2 = *(const float4*)(s1 + 4);
                o[0] = (unsigned)f2bf(omv * a1.x + mxv * b1.x) | ((unsigned)f2bf(omv * a1.y + mxv * b1.y) << 16);
                o[1] = (unsigned)f2bf(omv * a1.z + mxv * b1.z) | ((unsigned)f2bf(omv * a1.w + mxv * b1.w) << 16);
                o[2] = (unsigned)f2bf(omv * a2.x + mxv * b2.x) | ((unsigned)f2bf(omv * a2.y + mxv * b2.y) << 16);
                o[3] = (unsigned)f2bf(omv * a2.z + mxv * b2.z) | ((unsigned)f2bf(omv * a2.w + mxv * b2.w) << 16);
            }
            ra[j] = o;
        }
        #pragma unroll
        for (int j = 0; j < 2; ++j) {
            int id = tid + 256 * j; int r = id >> 3, s = id & 7;
            rb[j] = *(const uint32x4*)&Bt[(size_t)(n0 + r) * K + k0 + s * 8];
        }
    };

    LOADK(0);
    #pragma unroll 1
    for (int step = 0; step < K / 64; ++step) {
        __syncthreads();
        #pragma unroll
        for (int j = 0; j < 4; ++j) {
            int id = tid + 256 * j; int r = id >> 3, s = id & 7;
            *(uint32x4*)&As[r][s * 8] = ra[j];
        }
        #pragma unroll
        for (int j = 0; j < 2; ++j) {
            int id = tid + 256 * j; int r = id >> 3, s = id & 7;
            *(uint32x4*)&Bs[r][s * 8] = rb[j];
        }
        __syncthreads();
        if (step + 1 < K / 64) LOADK((step + 1) * 64);
        #pragma unroll
        for (int kk = 0; kk < 64; kk += 32) {
            bf16x8 b0 = __builtin_bit_cast(bf16x8, *(const uint32x4*)&Bs[wc * 32 + lr][kk + kb * 8]);
            bf16x8 b1 = __builtin_bit_cast(bf16x8, *(const uint32x4*)&Bs[wc * 32 + 16 + lr][kk + kb * 8]);
            #pragma unroll
            for (int mf = 0; mf < 4; ++mf) {
                bf16x8 a0 = __builtin_bit_cast(bf16x8, *(const uint32x4*)&As[wr * 64 + mf * 16 + lr][kk + kb * 8]);
                acc[mf][0] = __builtin_amdgcn_mfma_f32_16x16x32_bf16(a0, b0, acc[mf][0], 0, 0, 0);
                acc[mf][1] = __builtin_amdgcn_mfma_f32_16x16x32_bf16(a0, b1, acc[mf][1], 0, 0, 0);
            }
        }
    }

    #pragma unroll
    for (int nf = 0; nf < 2; ++nf) {
        const int col = n0 + wc * 32 + nf * 16 + lr;
        const float bv = bout[col];
        #pragma unroll
        for (int mf = 0; mf < 4; ++mf) {
            const int row = m0 + wr * 64 + mf * 16 + kb * 4;
            #pragma unroll
            for (int r = 0; r < 4; ++r)
                out[(size_t)(row + r) * 512 + col] = acc[mf][nf][r] + bv;
        }
    }
}

// ---------------------------------------------------------------------------
// Fused scores + softmax + context. 512 thr, grid (32,32) = 1024 blocks =
// 4 blocks/CU (32 waves). NO swizzle anywhere: thread (t, sr, oct) owns the
// strided d-chunk set {8j+oct}, so staging stores AND compute reads are both
// lane-consecutive 16B chunks -> conflict-free. v (x2, bf16) in LDS, read at
// the same chunk index. 3 LDS b128 reads per 8 elements.
// ---------------------------------------------------------------------------
__global__ __launch_bounds__(512, 8)
void attn_fused(const unsigned short* __restrict__ wq,  // [B,T,D] bf16, (.+bq)*C2
                const unsigned short* __restrict__ uh,  // [B,S,D] bf16
                const float* __restrict__ v,            // [D] f32
                const unsigned short* __restrict__ mem, // [B,S,D] bf16
                unsigned short* __restrict__ c_out)     // [B,T,D] bf16
{
    __shared__ __align__(16) unsigned short s_wq[TT4 * RW];
    __shared__ __align__(16) unsigned short s_uh[SCH16 * RW];
    __shared__ __align__(16) unsigned short s_v2[DD];
    __shared__ float s_sc[TT4 * SS];

    const int b = blockIdx.y, t0 = blockIdx.x * TT4;
    const int tid = threadIdx.x;

    // ---- stage wq tile + v2 (linear layout) ----
    if (tid < 256) {
        const int row = tid >> 6, G = tid & 63;
        *(uint32x4*)&s_wq[row * RW + G * 8] =
            *(const uint32x4*)&wq[((size_t)b * SS + t0 + row) * DD + G * 8];
    } else if (tid < 320) {
        const int H = tid - 256;                       // 0..63
        const float4 p = *(const float4*)&v[H * 8];
        const float4 q = *(const float4*)&v[H * 8 + 4];
        uint32x4 o;
        o[0] = (unsigned)f2bf(p.x * 2.f) | ((unsigned)f2bf(p.y * 2.f) << 16);
        o[1] = (unsigned)f2bf(p.z * 2.f) | ((unsigned)f2bf(p.w * 2.f) << 16);
        o[2] = (unsigned)f2bf(q.x * 2.f) | ((unsigned)f2bf(q.y * 2.f) << 16);
        o[3] = (unsigned)f2bf(q.z * 2.f) | ((unsigned)f2bf(q.w * 2.f) << 16);
        *(uint32x4*)&s_v2[H * 8] = o;
    }

    const int oct = tid & 7;            // d-chunks {8j+oct}, j=0..7
    const int sr  = (tid >> 3) & 15;    // s within chunk
    const int t   = tid >> 7;           // 0..3

    // ---- phase A: scores ----
    for (int sc0 = 0; sc0 < SS; sc0 += SCH16) {
        __syncthreads();                // prev chunk consumed (+ wq/v2 staged, 1st iter)
        {
            int i = tid;
            #pragma unroll
            for (int rep = 0; rep < 2; ++rep, i += 512) {
                const int row = i >> 6, G = i & 63;
                *(uint32x4*)&s_uh[row * RW + G * 8] =
                    *(const uint32x4*)&uh[((size_t)b * SS + sc0 + row) * DD + G * 8];
            }
        }
        __syncthreads();

        const unsigned short* wrow = &s_wq[t * RW];
        const unsigned short* urow = &s_uh[sr * RW];

        float a0 = 0.f, a1 = 0.f, a2 = 0.f, a3 = 0.f;
        #pragma unroll
        for (int j = 0; j < 8; ++j) {
            const int ch = (8 * j + oct) * 8;
            const uint32x4 w4 = *(const uint32x4*)&wrow[ch];
            const uint32x4 u4 = *(const uint32x4*)&urow[ch];
            const uint32x4 v4 = *(const uint32x4*)&s_v2[ch];
            float x, e;
            x = fmaf(C2F, bflo(u4[0]), bflo(w4[0])); e = __builtin_amdgcn_exp2f(x);
            a0 = fmaf(bflo(v4[0]), __builtin_amdgcn_rcpf(e + 1.f), a0);
            x = fmaf(C2F, bfhi(u4[0]), bfhi(w4[0])); e = __builtin_amdgcn_exp2f(x);
            a1 = fmaf(bfhi(v4[0]), __builtin_amdgcn_rcpf(e + 1.f), a1);
            x = fmaf(C2F, bflo(u4[1]), bflo(w4[1])); e = __builtin_amdgcn_exp2f(x);
            a2 = fmaf(bflo(v4[1]), __builtin_amdgcn_rcpf(e + 1.f), a2);
            x = fmaf(C2F, bfhi(u4[1]), bfhi(w4[1])); e = __builtin_amdgcn_exp2f(x);
            a3 = fmaf(bfhi(v4[1]), __builtin_amdgcn_rcpf(e + 1.f), a3);
            x = fmaf(C2F, bflo(u4[2]), bflo(w4[2])); e = __builtin_amdgcn_exp2f(x);
            a0 = fmaf(bflo(v4[2]), __builtin_amdgcn_rcpf(e + 1.f), a0);
            x = fmaf(C2F, bfhi(u4[2]), bfhi(w4[2])); e = __builtin_amdgcn_exp2f(x);
            a1 = fmaf(bfhi(v4[2]), __builtin_amdgcn_rcpf(e + 1.f), a1);
            x = fmaf(C2F, bflo(u4[3]), bflo(w4[3])); e = __builtin_amdgcn_exp2f(x);
            a2 = fmaf(bflo(v4[3]), __builtin_amdgcn_rcpf(e + 1.f), a2);
            x = fmaf(C2F, bfhi(u4[3]), bfhi(w4[3])); e = __builtin_amdgcn_exp2f(x);
            a3 = fmaf(bfhi(v4[3]), __builtin_amdgcn_rcpf(e + 1.f), a3);
        }
        float p = (a0 + a1) + (a2 + a3);
        p += __shfl_xor(p, 1);
        p += __shfl_xor(p, 2);
        p += __shfl_xor(p, 4);
        if (oct == 0) s_sc[t * SS + sc0 + sr] = -p;
    }
    __syncthreads();

    // ---- softmax: 4 rows x 128, threads 0..127 (32-lane groups) ----
    if (tid < 128) {
        const int tr = tid >> 5, l32 = tid & 31;
        float x0 = s_sc[tr * SS + l32];
        float x1 = s_sc[tr * SS + l32 + 32];
        float x2 = s_sc[tr * SS + l32 + 64];
        float x3 = s_sc[tr * SS + l32 + 96];
        float mx = fmaxf(fmaxf(x0, x1), fmaxf(x2, x3));
        #pragma unroll
        for (int off = 16; off > 0; off >>= 1) mx = fmaxf(mx, __shfl_xor(mx, off));
        const float e0 = __builtin_amdgcn_exp2f((x0 - mx) * L2EF);
        const float e1 = __builtin_amdgcn_exp2f((x1 - mx) * L2EF);
        const float e2 = __builtin_amdgcn_exp2f((x2 - mx) * L2EF);
        const float e3 = __builtin_amdgcn_exp2f((x3 - mx) * L2EF);
        float sum = (e0 + e1) + (e2 + e3);
        #pragma unroll
        for (int off = 16; off > 0; off >>= 1) sum += __shfl_xor(sum, off);
        const float rs = __builtin_amdgcn_rcpf(sum);
        s_sc[tr * SS + l32]      = e0 * rs;
        s_sc[tr * SS + l32 + 32] = e1 * rs;
        s_sc[tr * SS + l32 + 64] = e2 * rs;
        s_sc[tr * SS + l32 + 96] = e3 * rs;
    }

    // ---- phase B: context from LDS-staged mem (bf16) ----
    const int w = tid >> 6, lane = tid & 63;
    const int tb = w & 3, half = w >> 2;
    const int d = half * 256 + lane * 4;          // 4 shorts per thread
    f32x4 ac = {0.f, 0.f, 0.f, 0.f};

    for (int sc0 = 0; sc0 < SS; sc0 += SCH16) {
        __syncthreads();                // softmax done / prev chunk consumed
        {
            int i = tid;
            #pragma unroll
            for (int rep = 0; rep < 2; ++rep, i += 512) {
                const int row = i >> 6, G = i & 63;
                *(uint32x4*)&s_uh[row * RW + G * 8] =
                    *(const uint32x4*)&mem[((size_t)b * SS + sc0 + row) * DD + G * 8];
            }
        }
        __syncthreads();
        #pragma unroll
        for (int srow = 0; srow < SCH16; ++srow) {
            const float e = s_sc[tb * SS + sc0 + srow];
            const uint2 mv = *(const uint2*)&s_uh[srow * RW + d];
            ac[0] = fmaf(e, bflo(mv.x), ac[0]);
            ac[1] = fmaf(e, bfhi(mv.x), ac[1]);
            ac[2] = fmaf(e, bflo(mv.y), ac[2]);
            ac[3] = fmaf(e, bfhi(mv.y), ac[3]);
        }
    }
    uint2 st;
    st.x = (unsigned)f2bf(ac[0]) | ((unsigned)f2bf(ac[1]) << 16);
    st.y = (unsigned)f2bf(ac[2]) | ((unsigned)f2bf(ac[3]) << 16);
    *(uint2*)&c_out[((size_t)b * SS + t0 + tb) * DD + d] = st;
}

// ---------------------------------------------------------------------------
extern "C" void kernel_launch(void* const* d_in, const int* in_sizes, int n_in,
                              void* d_out, int out_size, void* d_ws, size_t ws_size,
                              hipStream_t stream) {
    const float* cs   = (const float*)d_in[0];
    const float* no   = (const float*)d_in[1];
    const float* Wq   = (const float*)d_in[2];
    const float* bq   = (const float*)d_in[3];
    const float* Wc   = (const float*)d_in[4];
    const float* v    = (const float*)d_in[5];
    const float* Wout = (const float*)d_in[6];
    const float* bout = (const float*)d_in[7];
    const float* mix  = (const float*)d_in[8];
    float* out = (float*)d_out;

    typedef unsigned short us;
    char* ws = (char*)d_ws;
    us* cs_bf = (us*)(ws);                     //  0..4 MB
    us* no_bf = (us*)(ws + (4u  << 20));       //  4..8 MB
    us* Wqct  = (us*)(ws + (8u  << 20));       //  8..9 MB   [1024][512] = Wq^T | Wc^T
    us* Woutt = (us*)(ws + (9u  << 20));       //  9..10 MB  [512][1024]
    us* wq1   = (us*)(ws + (10u << 20));       // 10..14 MB
    us* uh2   = (us*)(ws + (14u << 20));       // 14..18 MB
    us* wq2   = (us*)(ws + (18u << 20));       // 18..22 MB
    us* uh1   = (us*)(ws + (22u << 20));       // 22..26 MB
    us* c1    = (us*)(ws + (26u << 20));       // 26..30 MB
    us* c2    = (us*)(ws + (10u << 20));       // overlays wq1 (dead after attn1)

    const dim3 b256(256);
    const int n8 = 4096 * DD / 8;              // 262144

    cvt_dual<<<dim3(2 * n8 / 256), b256, 0, stream>>>(cs, no, cs_bf, no_bf, n8);
    transpose_all<<<dim3(8, 8, 4), b256, 0, stream>>>(Wq, Wc, Wout, Wqct, Woutt);

    // proj (z=0: A=no -> wq1|uh2 ; z=1: A=cs -> wq2|uh1)
    gemm_proj<<<dim3(16, 32, 2), b256, 0, stream>>>(no_bf, cs_bf, Wqct, bq,
                                                    wq1, uh2, wq2, uh1);

    // attn: dir1 (source=no, memory=cs), dir2 (source=cs, memory=no)
    attn_fused<<<dim3(32, 32), dim3(512), 0, stream>>>(wq1, uh1, v, cs_bf, c1);
    attn_fused<<<dim3(32, 32), dim3(512), 0, stream>>>(wq2, uh2, v, no_bf, c2);

    // final: [mix(c1,c2) | mix(no,cs)] @ Wout + bout
    gemm_final<<<dim3(8, 32), b256, 0, stream>>>(c1, c2, no, cs, mix, Woutt, bout, out);
}

// Round 9
// 302.885 us; speedup vs baseline: 1.1125x; 1.1125x over previous
//
#include <hip/hip_runtime.h>

// B=32, L=T=S=128, D=512, M = B*L = 4096.
#define DD 512
#define SS 128
#define TT4 4          // t-rows per attn block
#define SCH16 16       // s-chunk rows staged in LDS
#define RW 520         // LDS row width in shorts (1040B = 65x16B, 16B-aligned)
#define C2F 2.8853900817779268f   // 2*log2(e)
#define L2EF 1.4426950408889634f

typedef __bf16 bf16x8 __attribute__((ext_vector_type(8)));
typedef float f32x4 __attribute__((ext_vector_type(4)));
typedef unsigned int uint32x4 __attribute__((ext_vector_type(4)));

__device__ __forceinline__ unsigned short f2bf(float f) {
    unsigned int u = __builtin_bit_cast(unsigned int, f);
    u += 0x7fffu + ((u >> 16) & 1u);            // RTNE
    return (unsigned short)(u >> 16);
}
__device__ __forceinline__ float bflo(unsigned int u) { return __builtin_bit_cast(float, u << 16); }
__device__ __forceinline__ float bfhi(unsigned int u) { return __builtin_bit_cast(float, u & 0xffff0000u); }

// ---------------------------------------------------------------------------
// f32 -> bf16 for BOTH activation tensors in one dispatch. grid = 2*n8/256.
// ---------------------------------------------------------------------------
__global__ __launch_bounds__(256)
void cvt_dual(const float* __restrict__ a, const float* __restrict__ b,
              unsigned short* __restrict__ oa, unsigned short* __restrict__ ob, int n8)
{
    int i = blockIdx.x * 256 + threadIdx.x;
    const float* in; unsigned short* out; int k;
    if (i < n8) { in = a; out = oa; k = i; }
    else        { in = b; out = ob; k = i - n8; }
    const float4 x = ((const float4*)in)[2 * k];
    const float4 y = ((const float4*)in)[2 * k + 1];
    uint32x4 o;
    o[0] = (unsigned)f2bf(x.x) | ((unsigned)f2bf(x.y) << 16);
    o[1] = (unsigned)f2bf(x.z) | ((unsigned)f2bf(x.w) << 16);
    o[2] = (unsigned)f2bf(y.x) | ((unsigned)f2bf(y.y) << 16);
    o[3] = (unsigned)f2bf(y.z) | ((unsigned)f2bf(y.w) << 16);
    ((uint32x4*)out)[k] = o;
}

// ---------------------------------------------------------------------------
// All weight transposes in one dispatch. grid (8, 8, 4).
// ---------------------------------------------------------------------------
__global__ __launch_bounds__(256)
void transpose_all(const float* __restrict__ Wq, const float* __restrict__ Wc,
                   const float* __restrict__ Wout,
                   unsigned short* __restrict__ Wqct, unsigned short* __restrict__ Woutt)
{
    __shared__ float t[64][65];
    const int z = blockIdx.z;
    const float* in; unsigned short* out; int R, r0;
    if (z == 0)      { in = Wq;   out = Wqct;             R = 512;  r0 = blockIdx.y * 64; }
    else if (z == 1) { in = Wc;   out = Wqct + 512 * 512; R = 512;  r0 = blockIdx.y * 64; }
    else             { in = Wout; out = Woutt;            R = 1024; r0 = (z - 2) * 512 + blockIdx.y * 64; }
    const int c0 = blockIdx.x * 64;
    const int tid = threadIdx.x;
    const int lc = tid & 63, lr = tid >> 6;
    #pragma unroll
    for (int i = 0; i < 16; ++i) {
        int r = lr + i * 4;
        t[r][lc] = in[(size_t)(r0 + r) * 512 + c0 + lc];
    }
    __syncthreads();
    #pragma unroll
    for (int i = 0; i < 16; ++i) {
        int rr = lr + i * 4;
        out[(size_t)(c0 + rr) * R + r0 + lc] = f2bf(t[lc][rr]);
    }
}

// ---------------------------------------------------------------------------
// Projection GEMM, 128x128 tile, z-batched over the two inputs.
// X[4096,512]bf16 @ Wqct[1024,512]^T:
//   cols <512 -> wq' = (X@Wq + bq)*C2  (bf16)
//   cols>=512 -> uh' = (X@Wc)*C2       (bf16)   [pre-scaled for E_u=exp2(uh')]
// BK=64, 256 thr (4 waves 2x2, 64x64 each, acc 4x4), reg-prefetch.
// Grid (8, 32, 2). LDS 36KB (LDA=72 pad: reads 2-way=free, b128 writes optimal).
// ---------------------------------------------------------------------------
__global__ __launch_bounds__(256)
void gemm_proj(const unsigned short* __restrict__ A0, const unsigned short* __restrict__ A1,
               const unsigned short* __restrict__ Bt, const float* __restrict__ bq,
               unsigned short* __restrict__ w0, unsigned short* __restrict__ u0,
               unsigned short* __restrict__ w1, unsigned short* __restrict__ u1)
{
    constexpr int K = 512, LDA = 72;
    __shared__ __align__(16) unsigned short As[128][LDA];
    __shared__ __align__(16) unsigned short Bs[128][LDA];

    const unsigned short* A = blockIdx.z ? A1 : A0;
    unsigned short* outW    = blockIdx.z ? w1 : w0;
    unsigned short* outU    = blockIdx.z ? u1 : u0;

    const int tid = threadIdx.x;
    const int n0 = blockIdx.x * 128, m0 = blockIdx.y * 128;
    const int lane = tid & 63, wid = tid >> 6;
    const int wr = wid >> 1, wc = wid & 1;
    const int lr = lane & 15, kb = lane >> 4;

    f32x4 acc[4][4] = {};
    uint32x4 ra[4], rb[4];

    auto LOADK = [&](int k0) {
        #pragma unroll
        for (int j = 0; j < 4; ++j) {
            int id = tid + 256 * j; int r = id >> 3, s = id & 7;
            ra[j] = *(const uint32x4*)&A[(size_t)(m0 + r) * K + k0 + s * 8];
            rb[j] = *(const uint32x4*)&Bt[(size_t)(n0 + r) * K + k0 + s * 8];
        }
    };

    LOADK(0);
    #pragma unroll 1
    for (int step = 0; step < K / 64; ++step) {
        __syncthreads();
        #pragma unroll
        for (int j = 0; j < 4; ++j) {
            int id = tid + 256 * j; int r = id >> 3, s = id & 7;
            *(uint32x4*)&As[r][s * 8] = ra[j];
            *(uint32x4*)&Bs[r][s * 8] = rb[j];
        }
        __syncthreads();
        if (step + 1 < K / 64) LOADK((step + 1) * 64);
        #pragma unroll
        for (int kk = 0; kk < 64; kk += 32) {
            bf16x8 bfr[4];
            #pragma unroll
            for (int nf = 0; nf < 4; ++nf)
                bfr[nf] = __builtin_bit_cast(bf16x8, *(const uint32x4*)&Bs[wc * 64 + nf * 16 + lr][kk + kb * 8]);
            #pragma unroll
            for (int mf = 0; mf < 4; ++mf) {
                bf16x8 a0 = __builtin_bit_cast(bf16x8, *(const uint32x4*)&As[wr * 64 + mf * 16 + lr][kk + kb * 8]);
                #pragma unroll
                for (int nf = 0; nf < 4; ++nf)
                    acc[mf][nf] = __builtin_amdgcn_mfma_f32_16x16x32_bf16(a0, bfr[nf], acc[mf][nf], 0, 0, 0);
            }
        }
    }

    #pragma unroll
    for (int nf = 0; nf < 4; ++nf) {
        const int col = n0 + wc * 64 + nf * 16 + lr;
        const float bv = (col < 512) ? bq[col] : 0.0f;
        #pragma unroll
        for (int mf = 0; mf < 4; ++mf) {
            const int row = m0 + wr * 64 + mf * 16 + kb * 4;
            #pragma unroll
            for (int r = 0; r < 4; ++r) {
                const float valf = acc[mf][nf][r];
                if (col < 512) outW[(size_t)(row + r) * 512 + col] = f2bf((valf + bv) * C2F);
                else           outU[(size_t)(row + r) * 512 + (col - 512)] = f2bf(valf * C2F);
            }
        }
    }
}

// ---------------------------------------------------------------------------
// Final GEMM, A fused on the fly (unchanged from R6 — proven):
// A[m][k] = k<512 ? mix(c1,c2)[m][k] (bf16) : mix(no,cs)[m][k-512] (f32->bf16)
// ---------------------------------------------------------------------------
__global__ __launch_bounds__(256)
void gemm_final(const unsigned short* __restrict__ c1, const unsigned short* __restrict__ c2,
                const float* __restrict__ no, const float* __restrict__ cs,
                const float* __restrict__ mix, const unsigned short* __restrict__ Bt,
                const float* __restrict__ bout, float* __restrict__ out)
{
    constexpr int K = 1024, LDA = 72;
    __shared__ __align__(16) unsigned short As[128][LDA];
    __shared__ __align__(16) unsigned short Bs[64][LDA];

    const int tid = threadIdx.x;
    const int n0 = blockIdx.x * 64, m0 = blockIdx.y * 128;
    const int lane = tid & 63, wid = tid >> 6;
    const int wr = wid >> 1, wc = wid & 1;
    const int lr = lane & 15, kb = lane >> 4;
    const float mxv = mix[0], omv = 1.0f - mxv;

    f32x4 acc[4][2] = {};
    uint32x4 ra[4], rb[2];

    auto LOADK = [&](int k0) {
        #pragma unroll
        for (int j = 0; j < 4; ++j) {
            int id = tid + 256 * j; int r = id >> 3, s = id & 7;
            const size_t row = m0 + r;
            const int k = k0 + s * 8;
            uint32x4 o;
            if (k < 512) {
                const uint32x4 x1 = *(const uint32x4*)&c1[row * 512 + k];
                const uint32x4 x2 = *(const uint32x4*)&c2[row * 512 + k];
                #pragma unroll
                for (int q = 0; q < 4; ++q) {
                    float lo = omv * bflo(x1[q]) + mxv * bflo(x2[q]);
                    float hi = omv * bfhi(x1[q]) + mxv * bfhi(x2[q]);
                    o[q] = (unsigned)f2bf(lo) | ((unsigned)f2bf(hi) << 16);
                }
            } else {
                const float* n1 = &no[row * 512 + k - 512];
                const float* s1 = &cs[row * 512 + k - 512];
                const float4 a1 = *(const float4*)n1, a2 = *(const float4*)(n1 + 4);
                const float4 b1 = *(const float4*)s1, b2 = *(const float4*)(s1 + 4);
                o[0] = (unsigned)f2bf(omv * a1.x + mxv * b1.x) | ((unsigned)f2bf(omv * a1.y + mxv * b1.y) << 16);
                o[1] = (unsigned)f2bf(omv * a1.z + mxv * b1.z) | ((unsigned)f2bf(omv * a1.w + mxv * b1.w) << 16);
                o[2] = (unsigned)f2bf(omv * a2.x + mxv * b2.x) | ((unsigned)f2bf(omv * a2.y + mxv * b2.y) << 16);
                o[3] = (unsigned)f2bf(omv * a2.z + mxv * b2.z) | ((unsigned)f2bf(omv * a2.w + mxv * b2.w) << 16);
            }
            ra[j] = o;
        }
        #pragma unroll
        for (int j = 0; j < 2; ++j) {
            int id = tid + 256 * j; int r = id >> 3, s = id & 7;
            rb[j] = *(const uint32x4*)&Bt[(size_t)(n0 + r) * K + k0 + s * 8];
        }
    };

    LOADK(0);
    #pragma unroll 1
    for (int step = 0; step < K / 64; ++step) {
        __syncthreads();
        #pragma unroll
        for (int j = 0; j < 4; ++j) {
            int id = tid + 256 * j; int r = id >> 3, s = id & 7;
            *(uint32x4*)&As[r][s * 8] = ra[j];
        }
        #pragma unroll
        for (int j = 0; j < 2; ++j) {
            int id = tid + 256 * j; int r = id >> 3, s = id & 7;
            *(uint32x4*)&Bs[r][s * 8] = rb[j];
        }
        __syncthreads();
        if (step + 1 < K / 64) LOADK((step + 1) * 64);
        #pragma unroll
        for (int kk = 0; kk < 64; kk += 32) {
            bf16x8 b0 = __builtin_bit_cast(bf16x8, *(const uint32x4*)&Bs[wc * 32 + lr][kk + kb * 8]);
            bf16x8 b1 = __builtin_bit_cast(bf16x8, *(const uint32x4*)&Bs[wc * 32 + 16 + lr][kk + kb * 8]);
            #pragma unroll
            for (int mf = 0; mf < 4; ++mf) {
                bf16x8 a0 = __builtin_bit_cast(bf16x8, *(const uint32x4*)&As[wr * 64 + mf * 16 + lr][kk + kb * 8]);
                acc[mf][0] = __builtin_amdgcn_mfma_f32_16x16x32_bf16(a0, b0, acc[mf][0], 0, 0, 0);
                acc[mf][1] = __builtin_amdgcn_mfma_f32_16x16x32_bf16(a0, b1, acc[mf][1], 0, 0, 0);
            }
        }
    }

    #pragma unroll
    for (int nf = 0; nf < 2; ++nf) {
        const int col = n0 + wc * 32 + nf * 16 + lr;
        const float bv = bout[col];
        #pragma unroll
        for (int mf = 0; mf < 4; ++mf) {
            const int row = m0 + wr * 64 + mf * 16 + kb * 4;
            #pragma unroll
            for (int r = 0; r < 4; ++r)
                out[(size_t)(row + r) * 512 + col] = acc[mf][nf][r] + bv;
        }
    }
}

// ---------------------------------------------------------------------------
// Fused scores + softmax + context, FACTORED EXP version.
//   sigma = 1/(1 + E_w*E_u), E_w = exp2(wq'), E_u = exp2(uh')   (both pre-C2-scaled)
//   score[t,s] = -sum_d 2*v[d]*sigma  (softmax shift-invariant)
// E_w: computed once per block (2K elems). E_u: computed at chunk staging
// (65K/block — 4x fewer exp2 than in-loop). Inner loop: 6 VALU + 1 rcp /elem.
// Phase B: direct global reads of bf16 mem (L2-resident; no staging).
// 512 thr, grid (32,32) = 1024 blocks = 4/CU.
// ---------------------------------------------------------------------------
__global__ __launch_bounds__(512, 8)
void attn_fused(const unsigned short* __restrict__ wq,  // [B,T,D] bf16, (wq+bq)*C2
                const unsigned short* __restrict__ uh,  // [B,S,D] bf16, uh*C2
                const float* __restrict__ v,            // [D] f32
                const unsigned short* __restrict__ mem, // [B,S,D] bf16
                unsigned short* __restrict__ c_out)     // [B,T,D] bf16
{
    __shared__ __align__(16) unsigned short s_ew[TT4 * RW];    // E_w bf16
    __shared__ __align__(16) unsigned short s_eu[SCH16 * RW];  // E_u bf16
    __shared__ __align__(16) unsigned short s_v2[DD];          // 2*v bf16
    __shared__ __align__(16) float s_sc[TT4 * SS];

    const int b = blockIdx.y, t0 = blockIdx.x * TT4;
    const int tid = threadIdx.x;

    // ---- stage E_w = exp2(wq') and v2 ----
    if (tid < 256) {
        const int row = tid >> 6, G = tid & 63;
        const uint32x4 w4 = *(const uint32x4*)&wq[((size_t)b * SS + t0 + row) * DD + G * 8];
        uint32x4 o;
        #pragma unroll
        for (int q = 0; q < 4; ++q) {
            const float e0 = __builtin_amdgcn_exp2f(bflo(w4[q]));
            const float e1 = __builtin_amdgcn_exp2f(bfhi(w4[q]));
            o[q] = (unsigned)f2bf(e0) | ((unsigned)f2bf(e1) << 16);
        }
        *(uint32x4*)&s_ew[row * RW + G * 8] = o;
    } else if (tid < 320) {
        const int H = tid - 256;                       // 0..63
        const float4 p = *(const float4*)&v[H * 8];
        const float4 q = *(const float4*)&v[H * 8 + 4];
        uint32x4 o;
        o[0] = (unsigned)f2bf(p.x * 2.f) | ((unsigned)f2bf(p.y * 2.f) << 16);
        o[1] = (unsigned)f2bf(p.z * 2.f) | ((unsigned)f2bf(p.w * 2.f) << 16);
        o[2] = (unsigned)f2bf(q.x * 2.f) | ((unsigned)f2bf(q.y * 2.f) << 16);
        o[3] = (unsigned)f2bf(q.z * 2.f) | ((unsigned)f2bf(q.w * 2.f) << 16);
        *(uint32x4*)&s_v2[H * 8] = o;
    }

    const int oct = tid & 7;            // d-chunks {8j+oct}, j=0..7
    const int sr  = (tid >> 3) & 15;    // s within chunk
    const int t   = tid >> 7;           // 0..3

    // ---- phase A: scores ----
    for (int sc0 = 0; sc0 < SS; sc0 += SCH16) {
        __syncthreads();                // prev chunk consumed (+ E_w/v2 staged, 1st iter)
        {
            int i = tid;
            #pragma unroll
            for (int rep = 0; rep < 2; ++rep, i += 512) {
                const int row = i >> 6, G = i & 63;
                const uint32x4 u4 = *(const uint32x4*)&uh[((size_t)b * SS + sc0 + row) * DD + G * 8];
                uint32x4 o;
                #pragma unroll
                for (int q = 0; q < 4; ++q) {
                    const unsigned e0 = __builtin_bit_cast(unsigned, __builtin_amdgcn_exp2f(bflo(u4[q])));
                    const unsigned e1 = __builtin_bit_cast(unsigned, __builtin_amdgcn_exp2f(bfhi(u4[q])));
                    o[q] = (e0 >> 16) | (e1 & 0xffff0000u);   // RTZ pack (E>0)
                }
                *(uint32x4*)&s_eu[row * RW + G * 8] = o;
            }
        }
        __syncthreads();

        const unsigned short* wrow = &s_ew[t * RW];
        const unsigned short* urow = &s_eu[sr * RW];

        float a0 = 0.f, a1 = 0.f, a2 = 0.f, a3 = 0.f;
        #pragma unroll
        for (int j = 0; j < 8; ++j) {
            const int ch = (8 * j + oct) * 8;
            const uint32x4 w4 = *(const uint32x4*)&wrow[ch];
            const uint32x4 u4 = *(const uint32x4*)&urow[ch];
            const uint32x4 v4 = *(const uint32x4*)&s_v2[ch];
            a0 = fmaf(bflo(v4[0]), __builtin_amdgcn_rcpf(fmaf(bflo(w4[0]), bflo(u4[0]), 1.f)), a0);
            a1 = fmaf(bfhi(v4[0]), __builtin_amdgcn_rcpf(fmaf(bfhi(w4[0]), bfhi(u4[0]), 1.f)), a1);
            a2 = fmaf(bflo(v4[1]), __builtin_amdgcn_rcpf(fmaf(bflo(w4[1]), bflo(u4[1]), 1.f)), a2);
            a3 = fmaf(bfhi(v4[1]), __builtin_amdgcn_rcpf(fmaf(bfhi(w4[1]), bfhi(u4[1]), 1.f)), a3);
            a0 = fmaf(bflo(v4[2]), __builtin_amdgcn_rcpf(fmaf(bflo(w4[2]), bflo(u4[2]), 1.f)), a0);
            a1 = fmaf(bfhi(v4[2]), __builtin_amdgcn_rcpf(fmaf(bfhi(w4[2]), bfhi(u4[2]), 1.f)), a1);
            a2 = fmaf(bflo(v4[3]), __builtin_amdgcn_rcpf(fmaf(bflo(w4[3]), bflo(u4[3]), 1.f)), a2);
            a3 = fmaf(bfhi(v4[3]), __builtin_amdgcn_rcpf(fmaf(bfhi(w4[3]), bfhi(u4[3]), 1.f)), a3);
        }
        float p = (a0 + a1) + (a2 + a3);
        p += __shfl_xor(p, 1);
        p += __shfl_xor(p, 2);
        p += __shfl_xor(p, 4);
        if (oct == 0) s_sc[t * SS + sc0 + sr] = -p;
    }
    __syncthreads();

    // ---- softmax: 4 rows x 128, threads 0..127 ----
    if (tid < 128) {
        const int tr = tid >> 5, l32 = tid & 31;
        float x0 = s_sc[tr * SS + l32];
        float x1 = s_sc[tr * SS + l32 + 32];
        float x2 = s_sc[tr * SS + l32 + 64];
        float x3 = s_sc[tr * SS + l32 + 96];
        float mx = fmaxf(fmaxf(x0, x1), fmaxf(x2, x3));
        #pragma unroll
        for (int off = 16; off > 0; off >>= 1) mx = fmaxf(mx, __shfl_xor(mx, off));
        const float e0 = __builtin_amdgcn_exp2f((x0 - mx) * L2EF);
        const float e1 = __builtin_amdgcn_exp2f((x1 - mx) * L2EF);
        const float e2 = __builtin_amdgcn_exp2f((x2 - mx) * L2EF);
        const float e3 = __builtin_amdgcn_exp2f((x3 - mx) * L2EF);
        float sum = (e0 + e1) + (e2 + e3);
        #pragma unroll
        for (int off = 16; off > 0; off >>= 1) sum += __shfl_xor(sum, off);
        const float rs = __builtin_amdgcn_rcpf(sum);
        s_sc[tr * SS + l32]      = e0 * rs;
        s_sc[tr * SS + l32 + 32] = e1 * rs;
        s_sc[tr * SS + l32 + 64] = e2 * rs;
        s_sc[tr * SS + l32 + 96] = e3 * rs;
    }
    __syncthreads();

    // ---- phase B: context, direct global bf16 reads (L2-resident) ----
    {
        const int w = tid >> 6, lane = tid & 63;
        const int tb = w & 3, half = w >> 2;
        const int d = half * 256 + lane * 4;          // 4 shorts per thread
        const unsigned short* mb = mem + (size_t)b * SS * DD + d;
        f32x4 ac = {0.f, 0.f, 0.f, 0.f};
        #pragma unroll 1
        for (int s = 0; s < SS; s += 4) {
            const float4 e4 = *(const float4*)&s_sc[tb * SS + s];   // broadcast
            #pragma unroll
            for (int q = 0; q < 4; ++q) {
                const float e = (q == 0) ? e4.x : (q == 1) ? e4.y : (q == 2) ? e4.z : e4.w;
                const uint2 mv = *(const uint2*)&mb[(size_t)(s + q) * DD];
                ac[0] = fmaf(e, bflo(mv.x), ac[0]);
                ac[1] = fmaf(e, bfhi(mv.x), ac[1]);
                ac[2] = fmaf(e, bflo(mv.y), ac[2]);
                ac[3] = fmaf(e, bfhi(mv.y), ac[3]);
            }
        }
        uint2 st;
        st.x = (unsigned)f2bf(ac[0]) | ((unsigned)f2bf(ac[1]) << 16);
        st.y = (unsigned)f2bf(ac[2]) | ((unsigned)f2bf(ac[3]) << 16);
        *(uint2*)&c_out[((size_t)b * SS + t0 + tb) * DD + d] = st;
    }
}

// ---------------------------------------------------------------------------
extern "C" void kernel_launch(void* const* d_in, const int* in_sizes, int n_in,
                              void* d_out, int out_size, void* d_ws, size_t ws_size,
                              hipStream_t stream) {
    const float* cs   = (const float*)d_in[0];
    const float* no   = (const float*)d_in[1];
    const float* Wq   = (const float*)d_in[2];
    const float* bq   = (const float*)d_in[3];
    const float* Wc   = (const float*)d_in[4];
    const float* v    = (const float*)d_in[5];
    const float* Wout = (const float*)d_in[6];
    const float* bout = (const float*)d_in[7];
    const float* mix  = (const float*)d_in[8];
    float* out = (float*)d_out;

    typedef unsigned short us;
    char* ws = (char*)d_ws;
    us* cs_bf = (us*)(ws);                     //  0..4 MB
    us* no_bf = (us*)(ws + (4u  << 20));       //  4..8 MB
    us* Wqct  = (us*)(ws + (8u  << 20));       //  8..9 MB   [1024][512] = Wq^T | Wc^T
    us* Woutt = (us*)(ws + (9u  << 20));       //  9..10 MB  [512][1024]
    us* wq1   = (us*)(ws + (10u << 20));       // 10..14 MB
    us* uh2   = (us*)(ws + (14u << 20));       // 14..18 MB
    us* wq2   = (us*)(ws + (18u << 20));       // 18..22 MB
    us* uh1   = (us*)(ws + (22u << 20));       // 22..26 MB
    us* c1    = (us*)(ws + (26u << 20));       // 26..30 MB
    us* c2    = (us*)(ws + (10u << 20));       // overlays wq1 (dead after attn1)

    const dim3 b256(256);
    const int n8 = 4096 * DD / 8;              // 262144

    cvt_dual<<<dim3(2 * n8 / 256), b256, 0, stream>>>(cs, no, cs_bf, no_bf, n8);
    transpose_all<<<dim3(8, 8, 4), b256, 0, stream>>>(Wq, Wc, Wout, Wqct, Woutt);

    // proj (z=0: A=no -> wq1|uh2 ; z=1: A=cs -> wq2|uh1), 128x128 tiles
    gemm_proj<<<dim3(8, 32, 2), b256, 0, stream>>>(no_bf, cs_bf, Wqct, bq,
                                                   wq1, uh2, wq2, uh1);

    // attn: dir1 (source=no, memory=cs), dir2 (source=cs, memory=no)
    attn_fused<<<dim3(32, 32), dim3(512), 0, stream>>>(wq1, uh1, v, cs_bf, c1);
    attn_fused<<<dim3(32, 32), dim3(512), 0, stream>>>(wq2, uh2, v, no_bf, c2);

    // final: [mix(c1,c2) | mix(no,cs)] @ Wout + bout
    gemm_final<<<dim3(8, 32), b256, 0, stream>>>(c1, c2, no, cs, mix, Woutt, bout, out);
}

// Round 12
// 285.476 us; speedup vs baseline: 1.1804x; 1.0610x over previous
//
#include <hip/hip_runtime.h>

// B=32, L=T=S=128, D=512, M = B*L = 4096.
#define DD 512
#define SS 128
#define TT4 4          // t-rows per attn block
#define SCH8 8         // s-chunk rows staged in LDS (f32)
#define RWF 516        // f32 LDS row stride (2064B: 16B-aligned, 4-bank row offset)
#define C2F 2.8853900817779268f   // 2*log2(e)
#define L2EF 1.4426950408889634f

typedef __bf16 bf16x8 __attribute__((ext_vector_type(8)));
typedef float f32x4 __attribute__((ext_vector_type(4)));
typedef unsigned int uint32x4 __attribute__((ext_vector_type(4)));

__device__ __forceinline__ unsigned short f2bf(float f) {
    unsigned int u = __builtin_bit_cast(unsigned int, f);
    u += 0x7fffu + ((u >> 16) & 1u);            // RTNE
    return (unsigned short)(u >> 16);
}
__device__ __forceinline__ float bflo(unsigned int u) { return __builtin_bit_cast(float, u << 16); }
__device__ __forceinline__ float bfhi(unsigned int u) { return __builtin_bit_cast(float, u & 0xffff0000u); }

// ---------------------------------------------------------------------------
// f32 -> bf16 for BOTH activation tensors in one dispatch. grid = 2*n8/256.
// ---------------------------------------------------------------------------
__global__ __launch_bounds__(256)
void cvt_dual(const float* __restrict__ a, const float* __restrict__ b,
              unsigned short* __restrict__ oa, unsigned short* __restrict__ ob, int n8)
{
    int i = blockIdx.x * 256 + threadIdx.x;
    const float* in; unsigned short* out; int k;
    if (i < n8) { in = a; out = oa; k = i; }
    else        { in = b; out = ob; k = i - n8; }
    const float4 x = ((const float4*)in)[2 * k];
    const float4 y = ((const float4*)in)[2 * k + 1];
    uint32x4 o;
    o[0] = (unsigned)f2bf(x.x) | ((unsigned)f2bf(x.y) << 16);
    o[1] = (unsigned)f2bf(x.z) | ((unsigned)f2bf(x.w) << 16);
    o[2] = (unsigned)f2bf(y.x) | ((unsigned)f2bf(y.y) << 16);
    o[3] = (unsigned)f2bf(y.z) | ((unsigned)f2bf(y.w) << 16);
    ((uint32x4*)out)[k] = o;
}

// ---------------------------------------------------------------------------
// All weight transposes in one dispatch. grid (8, 8, 4).
// ---------------------------------------------------------------------------
__global__ __launch_bounds__(256)
void transpose_all(const float* __restrict__ Wq, const float* __restrict__ Wc,
                   const float* __restrict__ Wout,
                   unsigned short* __restrict__ Wqct, unsigned short* __restrict__ Woutt)
{
    __shared__ float t[64][65];
    const int z = blockIdx.z;
    const float* in; unsigned short* out; int R, r0;
    if (z == 0)      { in = Wq;   out = Wqct;             R = 512;  r0 = blockIdx.y * 64; }
    else if (z == 1) { in = Wc;   out = Wqct + 512 * 512; R = 512;  r0 = blockIdx.y * 64; }
    else             { in = Wout; out = Woutt;            R = 1024; r0 = (z - 2) * 512 + blockIdx.y * 64; }
    const int c0 = blockIdx.x * 64;
    const int tid = threadIdx.x;
    const int lc = tid & 63, lr = tid >> 6;
    #pragma unroll
    for (int i = 0; i < 16; ++i) {
        int r = lr + i * 4;
        t[r][lc] = in[(size_t)(r0 + r) * 512 + c0 + lc];
    }
    __syncthreads();
    #pragma unroll
    for (int i = 0; i < 16; ++i) {
        int rr = lr + i * 4;
        out[(size_t)(c0 + rr) * R + r0 + lc] = f2bf(t[lc][rr]);
    }
}

// ---------------------------------------------------------------------------
// Projection GEMM, 128x128 tile, z-batched over the two inputs (unchanged).
// ---------------------------------------------------------------------------
__global__ __launch_bounds__(256)
void gemm_proj(const unsigned short* __restrict__ A0, const unsigned short* __restrict__ A1,
               const unsigned short* __restrict__ Bt, const float* __restrict__ bq,
               unsigned short* __restrict__ w0, unsigned short* __restrict__ u0,
               unsigned short* __restrict__ w1, unsigned short* __restrict__ u1)
{
    constexpr int K = 512, LDA = 72;
    __shared__ __align__(16) unsigned short As[128][LDA];
    __shared__ __align__(16) unsigned short Bs[128][LDA];

    const unsigned short* A = blockIdx.z ? A1 : A0;
    unsigned short* outW    = blockIdx.z ? w1 : w0;
    unsigned short* outU    = blockIdx.z ? u1 : u0;

    const int tid = threadIdx.x;
    const int n0 = blockIdx.x * 128, m0 = blockIdx.y * 128;
    const int lane = tid & 63, wid = tid >> 6;
    const int wr = wid >> 1, wc = wid & 1;
    const int lr = lane & 15, kb = lane >> 4;

    f32x4 acc[4][4] = {};
    uint32x4 ra[4], rb[4];

    auto LOADK = [&](int k0) {
        #pragma unroll
        for (int j = 0; j < 4; ++j) {
            int id = tid + 256 * j; int r = id >> 3, s = id & 7;
            ra[j] = *(const uint32x4*)&A[(size_t)(m0 + r) * K + k0 + s * 8];
            rb[j] = *(const uint32x4*)&Bt[(size_t)(n0 + r) * K + k0 + s * 8];
        }
    };

    LOADK(0);
    #pragma unroll 1
    for (int step = 0; step < K / 64; ++step) {
        __syncthreads();
        #pragma unroll
        for (int j = 0; j < 4; ++j) {
            int id = tid + 256 * j; int r = id >> 3, s = id & 7;
            *(uint32x4*)&As[r][s * 8] = ra[j];
            *(uint32x4*)&Bs[r][s * 8] = rb[j];
        }
        __syncthreads();
        if (step + 1 < K / 64) LOADK((step + 1) * 64);
        #pragma unroll
        for (int kk = 0; kk < 64; kk += 32) {
            bf16x8 bfr[4];
            #pragma unroll
            for (int nf = 0; nf < 4; ++nf)
                bfr[nf] = __builtin_bit_cast(bf16x8, *(const uint32x4*)&Bs[wc * 64 + nf * 16 + lr][kk + kb * 8]);
            #pragma unroll
            for (int mf = 0; mf < 4; ++mf) {
                bf16x8 a0 = __builtin_bit_cast(bf16x8, *(const uint32x4*)&As[wr * 64 + mf * 16 + lr][kk + kb * 8]);
                #pragma unroll
                for (int nf = 0; nf < 4; ++nf)
                    acc[mf][nf] = __builtin_amdgcn_mfma_f32_16x16x32_bf16(a0, bfr[nf], acc[mf][nf], 0, 0, 0);
            }
        }
    }

    #pragma unroll
    for (int nf = 0; nf < 4; ++nf) {
        const int col = n0 + wc * 64 + nf * 16 + lr;
        const float bv = (col < 512) ? bq[col] : 0.0f;
        #pragma unroll
        for (int mf = 0; mf < 4; ++mf) {
            const int row = m0 + wr * 64 + mf * 16 + kb * 4;
            #pragma unroll
            for (int r = 0; r < 4; ++r) {
                const float valf = acc[mf][nf][r];
                if (col < 512) outW[(size_t)(row + r) * 512 + col] = f2bf((valf + bv) * C2F);
                else           outU[(size_t)(row + r) * 512 + (col - 512)] = f2bf(valf * C2F);
            }
        }
    }
}

// ---------------------------------------------------------------------------
// Final GEMM, A fused on the fly (unchanged from R6 — proven).
// ---------------------------------------------------------------------------
__global__ __launch_bounds__(256)
void gemm_final(const unsigned short* __restrict__ c1, const unsigned short* __restrict__ c2,
                const float* __restrict__ no, const float* __restrict__ cs,
                const float* __restrict__ mix, const unsigned short* __restrict__ Bt,
                const float* __restrict__ bout, float* __restrict__ out)
{
    constexpr int K = 1024, LDA = 72;
    __shared__ __align__(16) unsigned short As[128][LDA];
    __shared__ __align__(16) unsigned short Bs[64][LDA];

    const int tid = threadIdx.x;
    const int n0 = blockIdx.x * 64, m0 = blockIdx.y * 128;
    const int lane = tid & 63, wid = tid >> 6;
    const int wr = wid >> 1, wc = wid & 1;
    const int lr = lane & 15, kb = lane >> 4;
    const float mxv = mix[0], omv = 1.0f - mxv;

    f32x4 acc[4][2] = {};
    uint32x4 ra[4], rb[2];

    auto LOADK = [&](int k0) {
        #pragma unroll
        for (int j = 0; j < 4; ++j) {
            int id = tid + 256 * j; int r = id >> 3, s = id & 7;
            const size_t row = m0 + r;
            const int k = k0 + s * 8;
            uint32x4 o;
            if (k < 512) {
                const uint32x4 x1 = *(const uint32x4*)&c1[row * 512 + k];
                const uint32x4 x2 = *(const uint32x4*)&c2[row * 512 + k];
                #pragma unroll
                for (int q = 0; q < 4; ++q) {
                    float lo = omv * bflo(x1[q]) + mxv * bflo(x2[q]);
                    float hi = omv * bfhi(x1[q]) + mxv * bfhi(x2[q]);
                    o[q] = (unsigned)f2bf(lo) | ((unsigned)f2bf(hi) << 16);
                }
            } else {
                const float* n1 = &no[row * 512 + k - 512];
                const float* s1 = &cs[row * 512 + k - 512];
                const float4 a1 = *(const float4*)n1, a2 = *(const float4*)(n1 + 4);
                const float4 b1 = *(const float4*)s1, b2 = *(const float4*)(s1 + 4);
                o[0] = (unsigned)f2bf(omv * a1.x + mxv * b1.x) | ((unsigned)f2bf(omv * a1.y + mxv * b1.y) << 16);
                o[1] = (unsigned)f2bf(omv * a1.z + mxv * b1.z) | ((unsigned)f2bf(omv * a1.w + mxv * b1.w) << 16);
                o[2] = (unsigned)f2bf(omv * a2.x + mxv * b2.x) | ((unsigned)f2bf(omv * a2.y + mxv * b2.y) << 16);
                o[3] = (unsigned)f2bf(omv * a2.z + mxv * b2.z) | ((unsigned)f2bf(omv * a2.w + mxv * b2.w) << 16);
            }
            ra[j] = o;
        }
        #pragma unroll
        for (int j = 0; j < 2; ++j) {
            int id = tid + 256 * j; int r = id >> 3, s = id & 7;
            rb[j] = *(const uint32x4*)&Bt[(size_t)(n0 + r) * K + k0 + s * 8];
        }
    };

    LOADK(0);
    #pragma unroll 1
    for (int step = 0; step < K / 64; ++step) {
        __syncthreads();
        #pragma unroll
        for (int j = 0; j < 4; ++j) {
            int id = tid + 256 * j; int r = id >> 3, s = id & 7;
            *(uint32x4*)&As[r][s * 8] = ra[j];
        }
        #pragma unroll
        for (int j = 0; j < 2; ++j) {
            int id = tid + 256 * j; int r = id >> 3, s = id & 7;
            *(uint32x4*)&Bs[r][s * 8] = rb[j];
        }
        __syncthreads();
        if (step + 1 < K / 64) LOADK((step + 1) * 64);
        #pragma unroll
        for (int kk = 0; kk < 64; kk += 32) {
            bf16x8 b0 = __builtin_bit_cast(bf16x8, *(const uint32x4*)&Bs[wc * 32 + lr][kk + kb * 8]);
            bf16x8 b1 = __builtin_bit_cast(bf16x8, *(const uint32x4*)&Bs[wc * 32 + 16 + lr][kk + kb * 8]);
            #pragma unroll
            for (int mf = 0; mf < 4; ++mf) {
                bf16x8 a0 = __builtin_bit_cast(bf16x8, *(const uint32x4*)&As[wr * 64 + mf * 16 + lr][kk + kb * 8]);
                acc[mf][0] = __builtin_amdgcn_mfma_f32_16x16x32_bf16(a0, b0, acc[mf][0], 0, 0, 0);
                acc[mf][1] = __builtin_amdgcn_mfma_f32_16x16x32_bf16(a0, b1, acc[mf][1], 0, 0, 0);
            }
        }
    }

    #pragma unroll
    for (int nf = 0; nf < 2; ++nf) {
        const int col = n0 + wc * 32 + nf * 16 + lr;
        const float bv = bout[col];
        #pragma unroll
        for (int mf = 0; mf < 4; ++mf) {
            const int row = m0 + wr * 64 + mf * 16 + kb * 4;
            #pragma unroll
            for (int r = 0; r < 4; ++r)
                out[(size_t)(row + r) * 512 + col] = acc[mf][nf][r] + bv;
        }
    }
}

// ---------------------------------------------------------------------------
// Fused scores + softmax + context. BOTH directions in one dispatch (grid.z=2).
// f32 LDS (no extracts) + paired reciprocal:
//   v0*s0 + v1*s1 = (v0*p1 + v1*p0) * rcp(p0*p1),  p_i = 1 + Ew_i*Eu_i
// Thread = (t[2b], sr[3b], oct4[4b]): owns 32 d's (f32 chunks 16j+oct4).
// LDS ~29KB -> 5 blocks/CU (grid 4-5/CU fully resident).
// ---------------------------------------------------------------------------
__global__ __launch_bounds__(512, 8)
void attn_fused(const unsigned short* __restrict__ wqA, const unsigned short* __restrict__ uhA,
                const unsigned short* __restrict__ memA, unsigned short* __restrict__ coutA,
                const unsigned short* __restrict__ wqB, const unsigned short* __restrict__ uhB,
                const unsigned short* __restrict__ memB, unsigned short* __restrict__ coutB,
                const float* __restrict__ v)
{
    __shared__ __align__(16) float s_ew[TT4 * RWF];    // E_w f32
    __shared__ __align__(16) float s_eu[SCH8 * RWF];   // E_u f32
    __shared__ __align__(16) float s_v2[DD];           // 2*v f32
    __shared__ __align__(16) float s_sc[TT4 * SS];

    const int z = blockIdx.z;
    const unsigned short* wq  = z ? wqB  : wqA;
    const unsigned short* uh  = z ? uhB  : uhA;
    const unsigned short* mem = z ? memB : memA;
    unsigned short* c_out     = z ? coutB : coutA;

    const int b = blockIdx.y, t0 = blockIdx.x * TT4;
    const int tid = threadIdx.x;

    // ---- stage E_w = exp2(wq') f32, and v2 f32 ----
    if (tid < 256) {
        const int row = tid >> 6, G = tid & 63;       // G: 8-f32 group
        const uint32x4 w4 = *(const uint32x4*)&wq[((size_t)b * SS + t0 + row) * DD + G * 8];
        f32x4 o0, o1;
        o0[0] = __builtin_amdgcn_exp2f(bflo(w4[0])); o0[1] = __builtin_amdgcn_exp2f(bfhi(w4[0]));
        o0[2] = __builtin_amdgcn_exp2f(bflo(w4[1])); o0[3] = __builtin_amdgcn_exp2f(bfhi(w4[1]));
        o1[0] = __builtin_amdgcn_exp2f(bflo(w4[2])); o1[1] = __builtin_amdgcn_exp2f(bfhi(w4[2]));
        o1[2] = __builtin_amdgcn_exp2f(bflo(w4[3])); o1[3] = __builtin_amdgcn_exp2f(bfhi(w4[3]));
        *(f32x4*)&s_ew[row * RWF + G * 8]     = o0;
        *(f32x4*)&s_ew[row * RWF + G * 8 + 4] = o1;
    } else if (tid < 320) {
        const int H = tid - 256;                      // 0..63, 8 f32 each
        float4 p = *(const float4*)&v[H * 8];
        float4 q = *(const float4*)&v[H * 8 + 4];
        p.x *= 2.f; p.y *= 2.f; p.z *= 2.f; p.w *= 2.f;
        q.x *= 2.f; q.y *= 2.f; q.z *= 2.f; q.w *= 2.f;
        *(float4*)&s_v2[H * 8]     = p;
        *(float4*)&s_v2[H * 8 + 4] = q;
    }

    const int oct4 = tid & 15;          // 16 d-groups; f32 chunks {16j+oct4}
    const int sr   = (tid >> 4) & 7;    // s within chunk
    const int t    = tid >> 7;          // 0..3

    // ---- phase A: scores ----
    for (int sc0 = 0; sc0 < SS; sc0 += SCH8) {
        __syncthreads();                // prev chunk consumed (+ E_w/v2 staged, 1st iter)
        {
            #pragma unroll
            for (int rep = 0; rep < 2; ++rep) {
                const int idx = tid + rep * 512;      // 0..1023 float4-chunks
                const int row = idx >> 7, c = idx & 127;
                const uint2 u2 = *(const uint2*)&uh[((size_t)b * SS + sc0 + row) * DD + c * 4];
                f32x4 o;
                o[0] = __builtin_amdgcn_exp2f(bflo(u2.x));
                o[1] = __builtin_amdgcn_exp2f(bfhi(u2.x));
                o[2] = __builtin_amdgcn_exp2f(bflo(u2.y));
                o[3] = __builtin_amdgcn_exp2f(bfhi(u2.y));
                *(f32x4*)&s_eu[row * RWF + c * 4] = o;
            }
        }
        __syncthreads();

        const float* wrow = &s_ew[t * RWF];
        const float* urow = &s_eu[sr * RWF];

        float a0 = 0.f, a1 = 0.f;
        #pragma unroll
        for (int j = 0; j < 8; ++j) {
            const int cf = (16 * j + oct4) * 4;
            const f32x4 w4 = *(const f32x4*)&wrow[cf];
            const f32x4 u4 = *(const f32x4*)&urow[cf];
            const f32x4 v4 = *(const f32x4*)&s_v2[cf];
            const float p0 = fmaf(w4[0], u4[0], 1.f);
            const float p1 = fmaf(w4[1], u4[1], 1.f);
            float n0 = v4[0] * p1; n0 = fmaf(v4[1], p0, n0);
            a0 = fmaf(n0, __builtin_amdgcn_rcpf(p0 * p1), a0);
            const float p2 = fmaf(w4[2], u4[2], 1.f);
            const float p3 = fmaf(w4[3], u4[3], 1.f);
            float n1 = v4[2] * p3; n1 = fmaf(v4[3], p2, n1);
            a1 = fmaf(n1, __builtin_amdgcn_rcpf(p2 * p3), a1);
        }
        float p = a0 + a1;
        p += __shfl_xor(p, 1);
        p += __shfl_xor(p, 2);
        p += __shfl_xor(p, 4);
        p += __shfl_xor(p, 8);
        if (oct4 == 0) s_sc[t * SS + sc0 + sr] = -p;
    }
    __syncthreads();

    // ---- softmax: 4 rows x 128, threads 0..127 ----
    if (tid < 128) {
        const int tr = tid >> 5, l32 = tid & 31;
        float x0 = s_sc[tr * SS + l32];
        float x1 = s_sc[tr * SS + l32 + 32];
        float x2 = s_sc[tr * SS + l32 + 64];
        float x3 = s_sc[tr * SS + l32 + 96];
        float mx = fmaxf(fmaxf(x0, x1), fmaxf(x2, x3));
        #pragma unroll
        for (int off = 16; off > 0; off >>= 1) mx = fmaxf(mx, __shfl_xor(mx, off));
        const float e0 = __builtin_amdgcn_exp2f((x0 - mx) * L2EF);
        const float e1 = __builtin_amdgcn_exp2f((x1 - mx) * L2EF);
        const float e2 = __builtin_amdgcn_exp2f((x2 - mx) * L2EF);
        const float e3 = __builtin_amdgcn_exp2f((x3 - mx) * L2EF);
        float sum = (e0 + e1) + (e2 + e3);
        #pragma unroll
        for (int off = 16; off > 0; off >>= 1) sum += __shfl_xor(sum, off);
        const float rs = __builtin_amdgcn_rcpf(sum);
        s_sc[tr * SS + l32]      = e0 * rs;
        s_sc[tr * SS + l32 + 32] = e1 * rs;
        s_sc[tr * SS + l32 + 64] = e2 * rs;
        s_sc[tr * SS + l32 + 96] = e3 * rs;
    }
    __syncthreads();

    // ---- phase B: context, direct global bf16 reads (L2-resident) ----
    {
        const int w = tid >> 6, lane = tid & 63;
        const int tb = w & 3, half = w >> 2;
        const int d = half * 256 + lane * 4;          // 4 shorts per thread
        const unsigned short* mb = mem + (size_t)b * SS * DD + d;
        f32x4 ac = {0.f, 0.f, 0.f, 0.f};
        #pragma unroll 1
        for (int s = 0; s < SS; s += 4) {
            const float4 e4 = *(const float4*)&s_sc[tb * SS + s];   // broadcast
            #pragma unroll
            for (int q = 0; q < 4; ++q) {
                const float e = (q == 0) ? e4.x : (q == 1) ? e4.y : (q == 2) ? e4.z : e4.w;
                const uint2 mv = *(const uint2*)&mb[(size_t)(s + q) * DD];
                ac[0] = fmaf(e, bflo(mv.x), ac[0]);
                ac[1] = fmaf(e, bfhi(mv.x), ac[1]);
                ac[2] = fmaf(e, bflo(mv.y), ac[2]);
                ac[3] = fmaf(e, bfhi(mv.y), ac[3]);
            }
        }
        uint2 st;
        st.x = (unsigned)f2bf(ac[0]) | ((unsigned)f2bf(ac[1]) << 16);
        st.y = (unsigned)f2bf(ac[2]) | ((unsigned)f2bf(ac[3]) << 16);
        *(uint2*)&c_out[((size_t)b * SS + t0 + tb) * DD + d] = st;
    }
}

// ---------------------------------------------------------------------------
extern "C" void kernel_launch(void* const* d_in, const int* in_sizes, int n_in,
                              void* d_out, int out_size, void* d_ws, size_t ws_size,
                              hipStream_t stream) {
    const float* cs   = (const float*)d_in[0];
    const float* no   = (const float*)d_in[1];
    const float* Wq   = (const float*)d_in[2];
    const float* bq   = (const float*)d_in[3];
    const float* Wc   = (const float*)d_in[4];
    const float* v    = (const float*)d_in[5];
    const float* Wout = (const float*)d_in[6];
    const float* bout = (const float*)d_in[7];
    const float* mix  = (const float*)d_in[8];
    float* out = (float*)d_out;

    typedef unsigned short us;
    char* ws = (char*)d_ws;
    us* cs_bf = (us*)(ws);                     //  0..4 MB
    us* no_bf = (us*)(ws + (4u  << 20));       //  4..8 MB
    us* Wqct  = (us*)(ws + (8u  << 20));       //  8..9 MB   [1024][512] = Wq^T | Wc^T
    us* Woutt = (us*)(ws + (9u  << 20));       //  9..10 MB  [512][1024]
    us* wq1   = (us*)(ws + (10u << 20));       // 10..14 MB
    us* uh2   = (us*)(ws + (14u << 20));       // 14..18 MB
    us* wq2   = (us*)(ws + (18u << 20));       // 18..22 MB
    us* uh1   = (us*)(ws + (22u << 20));       // 22..26 MB
    us* c1    = (us*)(ws + (26u << 20));       // 26..30 MB
    us* c2    = (us*)(ws + (30u << 20));       // 30..34 MB

    const dim3 b256(256);
    const int n8 = 4096 * DD / 8;              // 262144

    cvt_dual<<<dim3(2 * n8 / 256), b256, 0, stream>>>(cs, no, cs_bf, no_bf, n8);
    transpose_all<<<dim3(8, 8, 4), b256, 0, stream>>>(Wq, Wc, Wout, Wqct, Woutt);

    // proj (z=0: A=no -> wq1|uh2 ; z=1: A=cs -> wq2|uh1), 128x128 tiles
    gemm_proj<<<dim3(8, 32, 2), b256, 0, stream>>>(no_bf, cs_bf, Wqct, bq,
                                                   wq1, uh2, wq2, uh1);

    // attn both directions in one dispatch:
    // z=0: (wq1, uh1, mem=cs) -> c1 ; z=1: (wq2, uh2, mem=no) -> c2
    attn_fused<<<dim3(32, 32, 2), dim3(512), 0, stream>>>(wq1, uh1, cs_bf, c1,
                                                          wq2, uh2, no_bf, c2, v);

    // final: [mix(c1,c2) | mix(no,cs)] @ Wout + bout
    gemm_final<<<dim3(8, 32), b256, 0, stream>>>(c1, c2, no, cs, mix, Woutt, bout, out);
}